// Round 9
// baseline (299.804 us; speedup 1.0000x reference)
//
#include <hip/hip_runtime.h>
#include <climits>

// Problem constants (fixed by reference setup_inputs)
constexpr int N_NODES = 50000;
constexpr int N_EDGES = 800000;
constexpr int DIM     = 128;
constexpr int DIM4    = DIM / 4;          // 32 float4 columns
constexpr float BN_EPS = 1e-5f;

constexpr int EMPTY = 0x7F7F7F7F;         // > any edge index; min-stable sentinel

// Owner-computes select: 128 blocks x 1024 threads; each block owns a node
// range with an LDS top-4 table and scans the whole dst[] (L2-resident).
constexpr int SEL_BLOCKS    = 128;
constexpr int SEL_THREADS   = 1024;
constexpr int NODES_PER_SEL = (N_NODES + SEL_BLOCKS - 1) / SEL_BLOCKS;   // 391

constexpr int NODES_PER_ITER  = 8;        // 256 threads / 32 float4-cols
constexpr int CONV_ITERS      = 3;
constexpr int NODES_PER_BLOCK = NODES_PER_ITER * CONV_ITERS;   // 24
constexpr int CONV_GRID = (N_NODES + NODES_PER_BLOCK - 1) / NODES_PER_BLOCK; // 2084

constexpr int NBUCKETS = 64;              // stats atomic spreading

// ---------------- float4 helpers ----------------
__device__ inline float4 f4min(float4 a, float4 b) {
    return make_float4(fminf(a.x,b.x), fminf(a.y,b.y), fminf(a.z,b.z), fminf(a.w,b.w));
}
__device__ inline float4 f4max(float4 a, float4 b) {
    return make_float4(fmaxf(a.x,b.x), fmaxf(a.y,b.y), fmaxf(a.z,b.z), fmaxf(a.w,b.w));
}
__device__ inline float4 f4add(float4 a, float4 b) {
    return make_float4(a.x+b.x, a.y+b.y, a.z+b.z, a.w+b.w);
}
__device__ inline float4 f4fma(float s, float4 v, float4 acc) {   // acc + s*v
    return make_float4(fmaf(s,v.x,acc.x), fmaf(s,v.y,acc.y), fmaf(s,v.z,acc.z), fmaf(s,v.w,acc.w));
}

// ---------------------------------------------------------------------------
// Owner-computes selection + remap in one kernel, LDS atomics only.
// Cascaded atomicMin = concurrent sorted insert of the 4 smallest edge
// indices per owned node (same algorithm proven in R5-R8, now on LDS).
// ---------------------------------------------------------------------------
__global__ __launch_bounds__(SEL_THREADS)
void select_scan_kernel(const int* __restrict__ dst,
                        const int* __restrict__ src,
                        int4* __restrict__ srcs4) {
    __shared__ int slot[NODES_PER_SEL * 4];

    const int r0    = blockIdx.x * NODES_PER_SEL;
    const int range = min(NODES_PER_SEL, N_NODES - r0);
    const int t     = threadIdx.x;

    for (int i = t; i < NODES_PER_SEL * 4; i += SEL_THREADS) slot[i] = EMPTY;
    __syncthreads();

    const int4* __restrict__ dst4 = (const int4*)dst;
    constexpr int E4 = N_EDGES / 4;       // 200000 exactly
    for (int i = t; i < E4; i += SEL_THREADS) {
        const int4 d = dst4[i];
        const int ebase = 4 * i;
        #define TRY_INS(comp, off) {                                        \
            unsigned n_ = (unsigned)(comp - r0);                            \
            if (n_ < (unsigned)range) {                                     \
                int cur_ = ebase + off;                                     \
                _Pragma("unroll")                                           \
                for (int j_ = 0; j_ < 4; ++j_) {                            \
                    int old_ = atomicMin(&slot[4 * n_ + j_], cur_);         \
                    if (old_ == EMPTY) break;                               \
                    cur_ = max(cur_, old_);                                 \
                } } }
        TRY_INS(d.x, 0); TRY_INS(d.y, 1); TRY_INS(d.z, 2); TRY_INS(d.w, 3);
        #undef TRY_INS
    }
    __syncthreads();

    // Owned nodes: map sorted edge indices -> src rows (-1 = empty slot).
    for (int n = t; n < range; n += SEL_THREADS) {
        int e0 = slot[4*n + 0], e1 = slot[4*n + 1];
        int e2 = slot[4*n + 2], e3 = slot[4*n + 3];
        int4 o;
        o.x = (e0 < N_EDGES) ? src[e0] : -1;
        o.y = (e1 < N_EDGES) ? src[e1] : -1;
        o.z = (e2 < N_EDGES) ? src[e2] : -1;
        o.w = (e3 < N_EDGES) ? src[e3] : -1;
        srcs4[r0 + n] = o;
    }
}

// blank_p[l] = W_l @ blank_l + b_l  (two 128x128 matvecs, blockIdx = layer)
__global__ void blank_proj_kernel(const float* __restrict__ W0, const float* __restrict__ b0,
                                  const float* __restrict__ bl0,
                                  const float* __restrict__ W1, const float* __restrict__ b1,
                                  const float* __restrict__ bl1,
                                  float* __restrict__ bp) {
    int l = blockIdx.x;
    int d = threadIdx.x;
    const float* W  = l ? W1  : W0;
    const float* b  = l ? b1  : b0;
    const float* bl = l ? bl1 : bl0;
    float s = 0.f;
    #pragma unroll 8
    for (int j = 0; j < DIM; ++j) s += W[d * DIM + j] * bl[j];
    bp[l * DIM + d] = s + b[d];
}

// ---------------------------------------------------------------------------
// Fused sort-conv + BN statistics (bucketed atomics). Identical to R8.
// Thread layout: d4 = tid&31 (float4 column), nsub = tid>>5 (8 nodes/iter).
// 24 nodes/block, 2084 blocks (8336 waves ~= device wave capacity).
// ---------------------------------------------------------------------------
__global__ __launch_bounds__(256)
void conv_stats_kernel(const float* __restrict__ x,
                       const int4* __restrict__ srcs4,    // per-node 4 gather rows
                       const float* __restrict__ bp,      // 128 floats (this layer)
                       const float* __restrict__ cw,
                       const float* __restrict__ cb,
                       const float* __restrict__ a,
                       float* __restrict__ h,
                       float* __restrict__ stats_part) {  // [NBUCKETS][256]
    const int t    = threadIdx.x;
    const int d4   = t & (DIM4 - 1);
    const int nsub = t >> 5;

    const float4* __restrict__ x4 = (const float4*)x;
    float4*       __restrict__ h4 = (float4*)h;

    const float aa = a[0];
    const float c0 = cw[0], c1 = cw[1], c2 = cw[2], c3 = cw[3];
    const float cbv = cb[0];
    const float4 bpv = ((const float4*)bp)[d4];

    float4 s  = make_float4(0.f, 0.f, 0.f, 0.f);
    float4 s2 = make_float4(0.f, 0.f, 0.f, 0.f);

    const int vbase = blockIdx.x * NODES_PER_BLOCK;
    #pragma unroll
    for (int it = 0; it < CONV_ITERS; ++it) {
        const int v = vbase + it * NODES_PER_ITER + nsub;
        if (v < N_NODES) {
            const int4 sv = srcs4[v];
            float4 m0 = (sv.x >= 0) ? x4[(size_t)sv.x * DIM4 + d4] : bpv;
            float4 m1 = (sv.y >= 0) ? x4[(size_t)sv.y * DIM4 + d4] : bpv;
            float4 m2 = (sv.z >= 0) ? x4[(size_t)sv.z * DIM4 + d4] : bpv;
            float4 m3 = (sv.w >= 0) ? x4[(size_t)sv.w * DIM4 + d4] : bpv;

            // component-wise 4-element sorting network (0,1)(2,3)(0,2)(1,3)(1,2)
            #define CSWAP4(p, q) { float4 lo = f4min(p, q); float4 hi = f4max(p, q); p = lo; q = hi; }
            CSWAP4(m0, m1); CSWAP4(m2, m3); CSWAP4(m0, m2); CSWAP4(m1, m3); CSWAP4(m1, m2);
            #undef CSWAP4

            float4 xv = x4[(size_t)v * DIM4 + d4];
            float4 hv = make_float4(cbv, cbv, cbv, cbv);
            hv = f4fma(c0, m0, hv);
            hv = f4fma(c1, m1, hv);
            hv = f4fma(c2, m2, hv);
            hv = f4fma(aa, xv, hv);
            hv = f4fma(c3, m3, hv);
            h4[(size_t)v * DIM4 + d4] = hv;

            s  = f4add(s, hv);
            s2 = f4add(s2, make_float4(hv.x*hv.x, hv.y*hv.y, hv.z*hv.z, hv.w*hv.w));
        }
    }

    // intra-wave: lane i += lane i+32 (same d4 column, different node)
    s.x  += __shfl_down(s.x, 32);  s.y  += __shfl_down(s.y, 32);
    s.z  += __shfl_down(s.z, 32);  s.w  += __shfl_down(s.w, 32);
    s2.x += __shfl_down(s2.x, 32); s2.y += __shfl_down(s2.y, 32);
    s2.z += __shfl_down(s2.z, 32); s2.w += __shfl_down(s2.w, 32);

    __shared__ float4 ls[4][32];
    __shared__ float4 ls2[4][32];
    const int wave = t >> 6;
    const int lane = t & 63;
    if (lane < 32) { ls[wave][lane] = s; ls2[wave][lane] = s2; }
    __syncthreads();
    if (t < 32) {
        float* bucket = stats_part + (size_t)(blockIdx.x & (NBUCKETS - 1)) * 256;
        float4 fs  = f4add(f4add(ls[0][t],  ls[1][t]),  f4add(ls[2][t],  ls[3][t]));
        float4 fs2 = f4add(f4add(ls2[0][t], ls2[1][t]), f4add(ls2[2][t], ls2[3][t]));
        atomicAdd(&bucket[4*t + 0], fs.x);
        atomicAdd(&bucket[4*t + 1], fs.y);
        atomicAdd(&bucket[4*t + 2], fs.z);
        atomicAdd(&bucket[4*t + 3], fs.w);
        atomicAdd(&bucket[DIM + 4*t + 0], fs2.x);
        atomicAdd(&bucket[DIM + 4*t + 1], fs2.y);
        atomicAdd(&bucket[DIM + 4*t + 2], fs2.z);
        atomicAdd(&bucket[DIM + 4*t + 3], fs2.w);
    }
}

// Sum the 64 bucket partials, finalize to mu (final[0:128]) and invstd (final[128:256]).
__global__ void reduce_finalize_kernel(const float* __restrict__ stats_part,
                                       float* __restrict__ final) {
    __shared__ float acc[256];
    int t = threadIdx.x;                 // 256 threads: t<128 sums, t>=128 sq-sums
    float s = 0.f;
    #pragma unroll 8
    for (int k = 0; k < NBUCKETS; ++k) s += stats_part[k * 256 + t];
    acc[t] = s;
    __syncthreads();
    if (t < 128) {
        constexpr float invN = 1.0f / (float)N_NODES;
        float mu = acc[t] * invN;
        float iv = rsqrtf(acc[128 + t] * invN - mu * mu + BN_EPS);
        final[t]       = mu;
        final[128 + t] = iv;
    }
}

// xout = xin + (h - mu) * invstd * g + be
__global__ void bn_apply_kernel(const float* __restrict__ xin,
                                const float* __restrict__ h,
                                const float* __restrict__ final,
                                const float* __restrict__ g,
                                const float* __restrict__ be,
                                float* __restrict__ xout) {
    int idx = blockIdx.x * blockDim.x + threadIdx.x;   // float4 index
    constexpr int TOTAL4 = N_NODES * DIM4;
    if (idx >= TOTAL4) return;
    int d4 = idx & (DIM4 - 1);

    float4 mu = ((const float4*)final)[d4];
    float4 iv = ((const float4*)(final + DIM))[d4];
    float4 hv = ((const float4*)h)[idx];
    float4 xv = ((const float4*)xin)[idx];
    float4 gv = ((const float4*)g)[d4];
    float4 bv = ((const float4*)be)[d4];

    float4 o;
    o.x = xv.x + (hv.x - mu.x) * iv.x * gv.x + bv.x;
    o.y = xv.y + (hv.y - mu.y) * iv.y * gv.y + bv.y;
    o.z = xv.z + (hv.z - mu.z) * iv.z * gv.z + bv.z;
    o.w = xv.w + (hv.w - mu.w) * iv.w * gv.w + bv.w;
    ((float4*)xout)[idx] = o;
}

extern "C" void kernel_launch(void* const* d_in, const int* in_sizes, int n_in,
                              void* d_out, int out_size, void* d_ws, size_t ws_size,
                              hipStream_t stream) {
    const float* x0  = (const float*)d_in[0];
    const int*   ei  = (const int*)d_in[1];
    const int*   src = ei;               // edge_index[0]
    const int*   dst = ei + N_EDGES;     // edge_index[1]

    const float* W[2]; const float* b[2]; const float* cw[2]; const float* cb[2];
    const float* a[2]; const float* g[2]; const float* be[2]; const float* blank[2];
    for (int i = 0; i < 2; ++i) {
        int o = 2 + 8 * i;
        W[i]     = (const float*)d_in[o + 0];
        b[i]     = (const float*)d_in[o + 1];
        cw[i]    = (const float*)d_in[o + 2];
        cb[i]    = (const float*)d_in[o + 3];
        a[i]     = (const float*)d_in[o + 4];
        g[i]     = (const float*)d_in[o + 5];
        be[i]    = (const float*)d_in[o + 6];
        blank[i] = (const float*)d_in[o + 7];
    }

    // Workspace layout (re-poisoned 0xAA each call — init everything used)
    char* ws = (char*)d_ws;
    int*   srcs       = (int*)ws;                                 // 4N ints, int4/node
    float* h          = (float*)(srcs + 4 * N_NODES);             // N*DIM floats = 25.6 MB
    float* stats_part = h + (size_t)N_NODES * DIM;                // 2 * 64 * 256 floats
    float* final_     = stats_part + 2 * NBUCKETS * 256;          // 2 * 256 floats
    float* bp         = final_ + 512;                             // 256 floats (2 layers)

    float* xout = (float*)d_out;

    // stats partials must start at zero (atomicAdd accumulation)
    hipMemsetAsync(stats_part, 0, 2 * NBUCKETS * 256 * sizeof(float), stream);

    // ---- owner-computes selection + remap (LDS atomics only) ----
    select_scan_kernel<<<SEL_BLOCKS, SEL_THREADS, 0, stream>>>(
        dst, src, (int4*)srcs);

    blank_proj_kernel<<<2, DIM, 0, stream>>>(W[0], b[0], blank[0],
                                             W[1], b[1], blank[1], bp);

    // ---- two layers ----
    for (int l = 0; l < 2; ++l) {
        const float* xin = (l == 0) ? x0 : xout;
        float* sp = stats_part + (size_t)l * NBUCKETS * 256;
        conv_stats_kernel<<<CONV_GRID, 256, 0, stream>>>(
            xin, (const int4*)srcs, bp + l * DIM, cw[l], cb[l], a[l], h, sp);
        reduce_finalize_kernel<<<1, 256, 0, stream>>>(sp, final_ + l * 256);
        bn_apply_kernel<<<(N_NODES * DIM4 + 255) / 256, 256, 0, stream>>>(
            xin, h, final_ + l * 256, g[l], be[l], xout);
    }
}

// Round 10
// 237.400 us; speedup vs baseline: 1.2629x; 1.2629x over previous
//
#include <hip/hip_runtime.h>
#include <climits>

// Problem constants (fixed by reference setup_inputs)
constexpr int N_NODES = 50000;
constexpr int N_EDGES = 800000;
constexpr int DIM     = 128;
constexpr int DIM4    = DIM / 4;          // 32 float4 columns
constexpr float BN_EPS = 1e-5f;

constexpr int EMPTY = 0x7F7F7F7F;         // > any edge index; min-stable sentinel

// Two-stage select: 16 node chunks x 16 edge chunks.
constexpr int NC = 16;
constexpr int EC = 16;
constexpr int NODES_PER_NC = N_NODES / NC;      // 3125 (50 KB LDS table)
constexpr int EDGES_PER_EC = N_EDGES / EC;      // 50000
constexpr int E4_PER_EC    = EDGES_PER_EC / 4;  // 12500 int4 loads per chunk

constexpr int NODES_PER_ITER  = 8;        // 256 threads / 32 float4-cols
constexpr int CONV_ITERS      = 2;
constexpr int NODES_PER_BLOCK = NODES_PER_ITER * CONV_ITERS;   // 16
constexpr int CONV_GRID = N_NODES / NODES_PER_BLOCK;           // 3125 exact, no guard

constexpr int NBUCKETS = 64;              // stats atomic spreading

// ---------------- float4 helpers ----------------
__device__ inline float4 f4min(float4 a, float4 b) {
    return make_float4(fminf(a.x,b.x), fminf(a.y,b.y), fminf(a.z,b.z), fminf(a.w,b.w));
}
__device__ inline float4 f4max(float4 a, float4 b) {
    return make_float4(fmaxf(a.x,b.x), fmaxf(a.y,b.y), fmaxf(a.z,b.z), fmaxf(a.w,b.w));
}
__device__ inline float4 f4add(float4 a, float4 b) {
    return make_float4(a.x+b.x, a.y+b.y, a.z+b.z, a.w+b.w);
}
__device__ inline float4 f4fma(float s, float4 v, float4 acc) {   // acc + s*v
    return make_float4(fmaf(s,v.x,acc.x), fmaf(s,v.y,acc.y), fmaf(s,v.z,acc.z), fmaf(s,v.w,acc.w));
}

// ---------------------------------------------------------------------------
// Select stage A: block (nc, ec) scans edge chunk ec, inserts edges whose dst
// lies in node chunk nc into an LDS top-4 table (cascaded LDS atomicMin =
// concurrent sorted insert, proven R5-R9), then streams the table to
// tables[ec][node] with plain coalesced stores (single writer per cell).
// ---------------------------------------------------------------------------
__global__ __launch_bounds__(256)
void select_stageA_kernel(const int* __restrict__ dst,
                          int* __restrict__ tables) {
    __shared__ int slot[NODES_PER_NC * 4];    // 50 KB
    const int nc = blockIdx.x & (NC - 1);
    const int ec = blockIdx.x >> 4;
    const int t  = threadIdx.x;

    for (int i = t; i < NODES_PER_NC * 4; i += 256) slot[i] = EMPTY;
    __syncthreads();

    const int r0 = nc * NODES_PER_NC;
    const int4* __restrict__ dst4 = (const int4*)dst;
    const int base4 = ec * E4_PER_EC;
    for (int i = t; i < E4_PER_EC; i += 256) {
        const int4 d = dst4[base4 + i];
        const int ebase = 4 * (base4 + i);
        #define TRY_INS(comp, off) {                                        \
            unsigned n_ = (unsigned)((comp) - r0);                          \
            if (n_ < (unsigned)NODES_PER_NC) {                              \
                int cur_ = ebase + (off);                                   \
                _Pragma("unroll")                                           \
                for (int j_ = 0; j_ < 4; ++j_) {                            \
                    int old_ = atomicMin(&slot[4 * n_ + j_], cur_);         \
                    if (old_ == EMPTY) break;                               \
                    cur_ = max(cur_, old_);                                 \
                } } }
        TRY_INS(d.x, 0); TRY_INS(d.y, 1); TRY_INS(d.z, 2); TRY_INS(d.w, 3);
        #undef TRY_INS
    }
    __syncthreads();

    int4* __restrict__ out = (int4*)tables + (size_t)ec * N_NODES + r0;
    const int4* __restrict__ sl4 = (const int4*)slot;
    for (int n = t; n < NODES_PER_NC; n += 256) out[n] = sl4[n];
}

// Select stage B: per node, merge the 16 per-chunk sorted top-4 candidate
// lists into the global top-4 (exact: every global top-4 edge is in its own
// chunk's top-4), then map edge index -> src row (-1 = empty).
__global__ void select_stageB_kernel(const int* __restrict__ tables,
                                     const int* __restrict__ src,
                                     int4* __restrict__ srcs4) {
    int v = blockIdx.x * blockDim.x + threadIdx.x;
    if (v >= N_NODES) return;

    int b0 = EMPTY, b1 = EMPTY, b2 = EMPTY, b3 = EMPTY;
    #pragma unroll
    for (int ec = 0; ec < EC; ++ec) {
        const int4 c = ((const int4*)tables)[(size_t)ec * N_NODES + v];
        #define INS(val) {                                          \
            int x_ = (val);                                         \
            if (x_ < b3) { b3 = x_;                                 \
                int tm;                                             \
                if (b3 < b2) { tm = b2; b2 = b3; b3 = tm; }         \
                if (b2 < b1) { tm = b1; b1 = b2; b2 = tm; }         \
                if (b1 < b0) { tm = b0; b0 = b1; b1 = tm; } } }
        INS(c.x); INS(c.y); INS(c.z); INS(c.w);
        #undef INS
    }
    int4 o;
    o.x = (b0 < N_EDGES) ? src[b0] : -1;
    o.y = (b1 < N_EDGES) ? src[b1] : -1;
    o.z = (b2 < N_EDGES) ? src[b2] : -1;
    o.w = (b3 < N_EDGES) ? src[b3] : -1;
    srcs4[v] = o;
}

// blank_p[l] = W_l @ blank_l + b_l  (two 128x128 matvecs, blockIdx = layer)
__global__ void blank_proj_kernel(const float* __restrict__ W0, const float* __restrict__ b0,
                                  const float* __restrict__ bl0,
                                  const float* __restrict__ W1, const float* __restrict__ b1,
                                  const float* __restrict__ bl1,
                                  float* __restrict__ bp) {
    int l = blockIdx.x;
    int d = threadIdx.x;
    const float* W  = l ? W1  : W0;
    const float* b  = l ? b1  : b0;
    const float* bl = l ? bl1 : bl0;
    float s = 0.f;
    #pragma unroll 8
    for (int j = 0; j < DIM; ++j) s += W[d * DIM + j] * bl[j];
    bp[l * DIM + d] = s + b[d];
}

// ---------------------------------------------------------------------------
// Fused sort-conv + BN statistics (bucketed atomics), ILP-restructured:
// exact grid (3125 x 16 nodes, no guard), both slot int4s loaded up-front,
// all 10 gathers unconditional (clamped index + select) -> ~12 loads in
// flight per thread instead of ~5.
// ---------------------------------------------------------------------------
__global__ __launch_bounds__(256)
void conv_stats_kernel(const float* __restrict__ x,
                       const int4* __restrict__ srcs4,    // per-node 4 gather rows
                       const float* __restrict__ bp,      // 128 floats (this layer)
                       const float* __restrict__ cw,
                       const float* __restrict__ cb,
                       const float* __restrict__ a,
                       float* __restrict__ h,
                       float* __restrict__ stats_part) {  // [NBUCKETS][256]
    const int t    = threadIdx.x;
    const int d4   = t & (DIM4 - 1);
    const int nsub = t >> 5;

    const float4* __restrict__ x4 = (const float4*)x;
    float4*       __restrict__ h4 = (float4*)h;

    const float aa = a[0];
    const float c0 = cw[0], c1 = cw[1], c2 = cw[2], c3 = cw[3];
    const float cbv = cb[0];
    const float4 bpv = ((const float4*)bp)[d4];

    const int v0 = blockIdx.x * NODES_PER_BLOCK + nsub;   // < N_NODES always
    const int v1 = v0 + NODES_PER_ITER;

    const int4 s0 = srcs4[v0];
    const int4 s1 = srcs4[v1];

    // unconditional gathers (clamped row), selects afterwards
    float4 g00 = x4[(size_t)max(s0.x, 0) * DIM4 + d4];
    float4 g01 = x4[(size_t)max(s0.y, 0) * DIM4 + d4];
    float4 g02 = x4[(size_t)max(s0.z, 0) * DIM4 + d4];
    float4 g03 = x4[(size_t)max(s0.w, 0) * DIM4 + d4];
    float4 g10 = x4[(size_t)max(s1.x, 0) * DIM4 + d4];
    float4 g11 = x4[(size_t)max(s1.y, 0) * DIM4 + d4];
    float4 g12 = x4[(size_t)max(s1.z, 0) * DIM4 + d4];
    float4 g13 = x4[(size_t)max(s1.w, 0) * DIM4 + d4];
    float4 xv0 = x4[(size_t)v0 * DIM4 + d4];
    float4 xv1 = x4[(size_t)v1 * DIM4 + d4];

    float4 s  = make_float4(0.f, 0.f, 0.f, 0.f);
    float4 s2 = make_float4(0.f, 0.f, 0.f, 0.f);

    #define CSWAP4(p, q) { float4 lo = f4min(p, q); float4 hi = f4max(p, q); p = lo; q = hi; }
    {
        float4 m0 = (s0.x >= 0) ? g00 : bpv;
        float4 m1 = (s0.y >= 0) ? g01 : bpv;
        float4 m2 = (s0.z >= 0) ? g02 : bpv;
        float4 m3 = (s0.w >= 0) ? g03 : bpv;
        CSWAP4(m0, m1); CSWAP4(m2, m3); CSWAP4(m0, m2); CSWAP4(m1, m3); CSWAP4(m1, m2);
        float4 hv = make_float4(cbv, cbv, cbv, cbv);
        hv = f4fma(c0, m0, hv);
        hv = f4fma(c1, m1, hv);
        hv = f4fma(c2, m2, hv);
        hv = f4fma(c3, m3, hv);
        hv = f4fma(aa, xv0, hv);
        h4[(size_t)v0 * DIM4 + d4] = hv;
        s  = f4add(s, hv);
        s2 = f4add(s2, make_float4(hv.x*hv.x, hv.y*hv.y, hv.z*hv.z, hv.w*hv.w));
    }
    {
        float4 m0 = (s1.x >= 0) ? g10 : bpv;
        float4 m1 = (s1.y >= 0) ? g11 : bpv;
        float4 m2 = (s1.z >= 0) ? g12 : bpv;
        float4 m3 = (s1.w >= 0) ? g13 : bpv;
        CSWAP4(m0, m1); CSWAP4(m2, m3); CSWAP4(m0, m2); CSWAP4(m1, m3); CSWAP4(m1, m2);
        float4 hv = make_float4(cbv, cbv, cbv, cbv);
        hv = f4fma(c0, m0, hv);
        hv = f4fma(c1, m1, hv);
        hv = f4fma(c2, m2, hv);
        hv = f4fma(c3, m3, hv);
        hv = f4fma(aa, xv1, hv);
        h4[(size_t)v1 * DIM4 + d4] = hv;
        s  = f4add(s, hv);
        s2 = f4add(s2, make_float4(hv.x*hv.x, hv.y*hv.y, hv.z*hv.z, hv.w*hv.w));
    }
    #undef CSWAP4

    // intra-wave: lane i += lane i+32 (same d4 column, different node)
    s.x  += __shfl_down(s.x, 32);  s.y  += __shfl_down(s.y, 32);
    s.z  += __shfl_down(s.z, 32);  s.w  += __shfl_down(s.w, 32);
    s2.x += __shfl_down(s2.x, 32); s2.y += __shfl_down(s2.y, 32);
    s2.z += __shfl_down(s2.z, 32); s2.w += __shfl_down(s2.w, 32);

    __shared__ float4 ls[4][32];
    __shared__ float4 ls2[4][32];
    const int wave = t >> 6;
    const int lane = t & 63;
    if (lane < 32) { ls[wave][lane] = s; ls2[wave][lane] = s2; }
    __syncthreads();
    if (t < 32) {
        float* bucket = stats_part + (size_t)(blockIdx.x & (NBUCKETS - 1)) * 256;
        float4 fs  = f4add(f4add(ls[0][t],  ls[1][t]),  f4add(ls[2][t],  ls[3][t]));
        float4 fs2 = f4add(f4add(ls2[0][t], ls2[1][t]), f4add(ls2[2][t], ls2[3][t]));
        atomicAdd(&bucket[4*t + 0], fs.x);
        atomicAdd(&bucket[4*t + 1], fs.y);
        atomicAdd(&bucket[4*t + 2], fs.z);
        atomicAdd(&bucket[4*t + 3], fs.w);
        atomicAdd(&bucket[DIM + 4*t + 0], fs2.x);
        atomicAdd(&bucket[DIM + 4*t + 1], fs2.y);
        atomicAdd(&bucket[DIM + 4*t + 2], fs2.z);
        atomicAdd(&bucket[DIM + 4*t + 3], fs2.w);
    }
}

// Sum the 64 bucket partials, finalize to mu (final[0:128]) and invstd (final[128:256]).
__global__ void reduce_finalize_kernel(const float* __restrict__ stats_part,
                                       float* __restrict__ final) {
    __shared__ float acc[256];
    int t = threadIdx.x;                 // 256 threads: t<128 sums, t>=128 sq-sums
    float s = 0.f;
    #pragma unroll 8
    for (int k = 0; k < NBUCKETS; ++k) s += stats_part[k * 256 + t];
    acc[t] = s;
    __syncthreads();
    if (t < 128) {
        constexpr float invN = 1.0f / (float)N_NODES;
        float mu = acc[t] * invN;
        float iv = rsqrtf(acc[128 + t] * invN - mu * mu + BN_EPS);
        final[t]       = mu;
        final[128 + t] = iv;
    }
}

// xout = xin + (h - mu) * invstd * g + be
__global__ void bn_apply_kernel(const float* __restrict__ xin,
                                const float* __restrict__ h,
                                const float* __restrict__ final,
                                const float* __restrict__ g,
                                const float* __restrict__ be,
                                float* __restrict__ xout) {
    int idx = blockIdx.x * blockDim.x + threadIdx.x;   // float4 index
    constexpr int TOTAL4 = N_NODES * DIM4;
    if (idx >= TOTAL4) return;
    int d4 = idx & (DIM4 - 1);

    float4 mu = ((const float4*)final)[d4];
    float4 iv = ((const float4*)(final + DIM))[d4];
    float4 hv = ((const float4*)h)[idx];
    float4 xv = ((const float4*)xin)[idx];
    float4 gv = ((const float4*)g)[d4];
    float4 bv = ((const float4*)be)[d4];

    float4 o;
    o.x = xv.x + (hv.x - mu.x) * iv.x * gv.x + bv.x;
    o.y = xv.y + (hv.y - mu.y) * iv.y * gv.y + bv.y;
    o.z = xv.z + (hv.z - mu.z) * iv.z * gv.z + bv.z;
    o.w = xv.w + (hv.w - mu.w) * iv.w * gv.w + bv.w;
    ((float4*)xout)[idx] = o;
}

extern "C" void kernel_launch(void* const* d_in, const int* in_sizes, int n_in,
                              void* d_out, int out_size, void* d_ws, size_t ws_size,
                              hipStream_t stream) {
    const float* x0  = (const float*)d_in[0];
    const int*   ei  = (const int*)d_in[1];
    const int*   src = ei;               // edge_index[0]
    const int*   dst = ei + N_EDGES;     // edge_index[1]

    const float* W[2]; const float* b[2]; const float* cw[2]; const float* cb[2];
    const float* a[2]; const float* g[2]; const float* be[2]; const float* blank[2];
    for (int i = 0; i < 2; ++i) {
        int o = 2 + 8 * i;
        W[i]     = (const float*)d_in[o + 0];
        b[i]     = (const float*)d_in[o + 1];
        cw[i]    = (const float*)d_in[o + 2];
        cb[i]    = (const float*)d_in[o + 3];
        a[i]     = (const float*)d_in[o + 4];
        g[i]     = (const float*)d_in[o + 5];
        be[i]    = (const float*)d_in[o + 6];
        blank[i] = (const float*)d_in[o + 7];
    }

    // Workspace layout (re-poisoned 0xAA each call — init everything used).
    // tables (stage A output, 16*N int4s = 12.8 MB) aliases the h region:
    // tables is dead before conv_stats writes h.
    char* ws = (char*)d_ws;
    int*   srcs       = (int*)ws;                                 // 4N ints, int4/node
    float* h          = (float*)(srcs + 4 * N_NODES);             // N*DIM floats = 25.6 MB
    int*   tables     = (int*)h;                                  // alias: 16*4N ints = 12.8 MB
    float* stats_part = h + (size_t)N_NODES * DIM;                // 2 * 64 * 256 floats
    float* final_     = stats_part + 2 * NBUCKETS * 256;          // 2 * 256 floats
    float* bp         = final_ + 512;                             // 256 floats (2 layers)

    float* xout = (float*)d_out;

    // stats partials must start at zero (atomicAdd accumulation)
    hipMemsetAsync(stats_part, 0, 2 * NBUCKETS * 256 * sizeof(float), stream);

    // ---- two-stage selection (LDS atomics only; streaming merge) ----
    select_stageA_kernel<<<NC * EC, 256, 0, stream>>>(dst, tables);
    select_stageB_kernel<<<(N_NODES + 255) / 256, 256, 0, stream>>>(
        tables, src, (int4*)srcs);

    blank_proj_kernel<<<2, DIM, 0, stream>>>(W[0], b[0], blank[0],
                                             W[1], b[1], blank[1], bp);

    // ---- two layers ----
    for (int l = 0; l < 2; ++l) {
        const float* xin = (l == 0) ? x0 : xout;
        float* sp = stats_part + (size_t)l * NBUCKETS * 256;
        conv_stats_kernel<<<CONV_GRID, 256, 0, stream>>>(
            xin, (const int4*)srcs, bp + l * DIM, cw[l], cb[l], a[l], h, sp);
        reduce_finalize_kernel<<<1, 256, 0, stream>>>(sp, final_ + l * 256);
        bn_apply_kernel<<<(N_NODES * DIM4 + 255) / 256, 256, 0, stream>>>(
            xin, h, final_ + l * 256, g[l], be[l], xout);
    }
}

// Round 11
// 207.937 us; speedup vs baseline: 1.4418x; 1.1417x over previous
//
#include <hip/hip_runtime.h>
#include <climits>

// Problem constants (fixed by reference setup_inputs)
constexpr int N_NODES = 50000;
constexpr int N_EDGES = 800000;
constexpr int DIM     = 128;
constexpr int DIM4    = DIM / 4;          // 32 float4 columns
constexpr float BN_EPS = 1e-5f;

constexpr int EMPTY = 0x7F7F7F7F;         // > any edge index; min-stable sentinel

// Two-stage select: 16 node chunks x 16 edge chunks, 1024-thread scan blocks.
constexpr int NC = 16;
constexpr int EC = 16;
constexpr int NODES_PER_NC = N_NODES / NC;      // 3125 (50 KB LDS table)
constexpr int EDGES_PER_EC = N_EDGES / EC;      // 50000
constexpr int E4_PER_EC    = EDGES_PER_EC / 4;  // 12500 int4 loads per chunk
constexpr int SEL_THREADS  = 1024;              // 16 waves/CU -> ~50% occupancy

constexpr int NODES_PER_ITER  = 8;        // 256 threads / 32 float4-cols
constexpr int CONV_ITERS      = 2;
constexpr int NODES_PER_BLOCK = NODES_PER_ITER * CONV_ITERS;   // 16
constexpr int CONV_GRID = N_NODES / NODES_PER_BLOCK;           // 3125 exact, no guard

constexpr int NBUCKETS = 64;              // stats atomic spreading
constexpr int NB_MERGE = (N_NODES + 255) / 256;   // 196 merge blocks in stage B

// ---------------- float4 helpers ----------------
__device__ inline float4 f4min(float4 a, float4 b) {
    return make_float4(fminf(a.x,b.x), fminf(a.y,b.y), fminf(a.z,b.z), fminf(a.w,b.w));
}
__device__ inline float4 f4max(float4 a, float4 b) {
    return make_float4(fmaxf(a.x,b.x), fmaxf(a.y,b.y), fmaxf(a.z,b.z), fmaxf(a.w,b.w));
}
__device__ inline float4 f4add(float4 a, float4 b) {
    return make_float4(a.x+b.x, a.y+b.y, a.z+b.z, a.w+b.w);
}
__device__ inline float4 f4fma(float s, float4 v, float4 acc) {   // acc + s*v
    return make_float4(fmaf(s,v.x,acc.x), fmaf(s,v.y,acc.y), fmaf(s,v.z,acc.z), fmaf(s,v.w,acc.w));
}

// ---------------------------------------------------------------------------
// Select stage A: block (nc, ec) scans edge chunk ec with 1024 threads,
// inserts edges whose dst lies in node chunk nc into an LDS top-4 table
// (cascaded LDS atomicMin = concurrent sorted insert), then streams the
// table to tables[ec][node] with plain coalesced stores (one writer/cell).
// ---------------------------------------------------------------------------
__global__ __launch_bounds__(SEL_THREADS)
void select_stageA_kernel(const int* __restrict__ dst,
                          int* __restrict__ tables) {
    __shared__ int slot[NODES_PER_NC * 4];    // 50 KB
    const int nc = blockIdx.x & (NC - 1);
    const int ec = blockIdx.x >> 4;
    const int t  = threadIdx.x;

    for (int i = t; i < NODES_PER_NC * 4; i += SEL_THREADS) slot[i] = EMPTY;
    __syncthreads();

    const int r0 = nc * NODES_PER_NC;
    const int4* __restrict__ dst4 = (const int4*)dst;
    const int base4 = ec * E4_PER_EC;
    for (int i = t; i < E4_PER_EC; i += SEL_THREADS) {
        const int4 d = dst4[base4 + i];
        const int ebase = 4 * (base4 + i);
        #define TRY_INS(comp, off) {                                        \
            unsigned n_ = (unsigned)((comp) - r0);                          \
            if (n_ < (unsigned)NODES_PER_NC) {                              \
                int cur_ = ebase + (off);                                   \
                _Pragma("unroll")                                           \
                for (int j_ = 0; j_ < 4; ++j_) {                            \
                    int old_ = atomicMin(&slot[4 * n_ + j_], cur_);         \
                    if (old_ == EMPTY) break;                               \
                    cur_ = max(cur_, old_);                                 \
                } } }
        TRY_INS(d.x, 0); TRY_INS(d.y, 1); TRY_INS(d.z, 2); TRY_INS(d.w, 3);
        #undef TRY_INS
    }
    __syncthreads();

    int4* __restrict__ out = (int4*)tables + (size_t)ec * N_NODES + r0;
    const int4* __restrict__ sl4 = (const int4*)slot;
    for (int n = t; n < NODES_PER_NC; n += SEL_THREADS) out[n] = sl4[n];
}

// ---------------------------------------------------------------------------
// Select stage B + housekeeping. Blocks [0, NB_MERGE): per node, merge the 16
// per-chunk sorted top-4 lists into the global top-4 (exact), map through src
// (-1 = empty); also zero stats_part. Blocks NB_MERGE / NB_MERGE+1: compute
// blank_p[l] = W_l @ blank_l + b_l (one 128x128 matvec each).
// ---------------------------------------------------------------------------
__global__ __launch_bounds__(256)
void select_stageB_kernel(const int* __restrict__ tables,
                          const int* __restrict__ src,
                          int4* __restrict__ srcs4,
                          float* __restrict__ stats_part,   // zeroed here
                          const float* __restrict__ W0, const float* __restrict__ b0,
                          const float* __restrict__ bl0,
                          const float* __restrict__ W1, const float* __restrict__ b1,
                          const float* __restrict__ bl1,
                          float* __restrict__ bp) {
    const int t = threadIdx.x;

    if (blockIdx.x >= NB_MERGE) {         // blank-projection blocks
        if (t < DIM) {
            int l = blockIdx.x - NB_MERGE;
            const float* W  = l ? W1  : W0;
            const float* b  = l ? b1  : b0;
            const float* bl = l ? bl1 : bl0;
            float s = 0.f;
            #pragma unroll 8
            for (int j = 0; j < DIM; ++j) s += W[t * DIM + j] * bl[j];
            bp[l * DIM + t] = s + b[t];
        }
        return;
    }

    const int gid = blockIdx.x * 256 + t;
    if (gid < 2 * NBUCKETS * 256) stats_part[gid] = 0.f;   // fold the memset

    const int v = gid;
    if (v >= N_NODES) return;

    int b0_ = EMPTY, b1_ = EMPTY, b2_ = EMPTY, b3_ = EMPTY;
    #pragma unroll
    for (int ec = 0; ec < EC; ++ec) {
        const int4 c = ((const int4*)tables)[(size_t)ec * N_NODES + v];
        if (c.x >= b3_) continue;         // chunk min can't improve top-4
        #define INS(val) {                                          \
            int x_ = (val);                                         \
            if (x_ < b3_) { b3_ = x_;                               \
                int tm;                                             \
                if (b3_ < b2_) { tm = b2_; b2_ = b3_; b3_ = tm; }   \
                if (b2_ < b1_) { tm = b1_; b1_ = b2_; b2_ = tm; }   \
                if (b1_ < b0_) { tm = b0_; b0_ = b1_; b1_ = tm; } } }
        INS(c.x); INS(c.y); INS(c.z); INS(c.w);
        #undef INS
    }
    int4 o;
    o.x = (b0_ < N_EDGES) ? src[b0_] : -1;
    o.y = (b1_ < N_EDGES) ? src[b1_] : -1;
    o.z = (b2_ < N_EDGES) ? src[b2_] : -1;
    o.w = (b3_ < N_EDGES) ? src[b3_] : -1;
    srcs4[v] = o;
}

// ---------------------------------------------------------------------------
// Fused sort-conv + BN statistics (bucketed atomics). Identical to R10.
// ---------------------------------------------------------------------------
__global__ __launch_bounds__(256)
void conv_stats_kernel(const float* __restrict__ x,
                       const int4* __restrict__ srcs4,    // per-node 4 gather rows
                       const float* __restrict__ bp,      // 128 floats (this layer)
                       const float* __restrict__ cw,
                       const float* __restrict__ cb,
                       const float* __restrict__ a,
                       float* __restrict__ h,
                       float* __restrict__ stats_part) {  // [NBUCKETS][256]
    const int t    = threadIdx.x;
    const int d4   = t & (DIM4 - 1);
    const int nsub = t >> 5;

    const float4* __restrict__ x4 = (const float4*)x;
    float4*       __restrict__ h4 = (float4*)h;

    const float aa = a[0];
    const float c0 = cw[0], c1 = cw[1], c2 = cw[2], c3 = cw[3];
    const float cbv = cb[0];
    const float4 bpv = ((const float4*)bp)[d4];

    const int v0 = blockIdx.x * NODES_PER_BLOCK + nsub;   // < N_NODES always
    const int v1 = v0 + NODES_PER_ITER;

    const int4 s0 = srcs4[v0];
    const int4 s1 = srcs4[v1];

    // unconditional gathers (clamped row), selects afterwards
    float4 g00 = x4[(size_t)max(s0.x, 0) * DIM4 + d4];
    float4 g01 = x4[(size_t)max(s0.y, 0) * DIM4 + d4];
    float4 g02 = x4[(size_t)max(s0.z, 0) * DIM4 + d4];
    float4 g03 = x4[(size_t)max(s0.w, 0) * DIM4 + d4];
    float4 g10 = x4[(size_t)max(s1.x, 0) * DIM4 + d4];
    float4 g11 = x4[(size_t)max(s1.y, 0) * DIM4 + d4];
    float4 g12 = x4[(size_t)max(s1.z, 0) * DIM4 + d4];
    float4 g13 = x4[(size_t)max(s1.w, 0) * DIM4 + d4];
    float4 xv0 = x4[(size_t)v0 * DIM4 + d4];
    float4 xv1 = x4[(size_t)v1 * DIM4 + d4];

    float4 s  = make_float4(0.f, 0.f, 0.f, 0.f);
    float4 s2 = make_float4(0.f, 0.f, 0.f, 0.f);

    #define CSWAP4(p, q) { float4 lo = f4min(p, q); float4 hi = f4max(p, q); p = lo; q = hi; }
    {
        float4 m0 = (s0.x >= 0) ? g00 : bpv;
        float4 m1 = (s0.y >= 0) ? g01 : bpv;
        float4 m2 = (s0.z >= 0) ? g02 : bpv;
        float4 m3 = (s0.w >= 0) ? g03 : bpv;
        CSWAP4(m0, m1); CSWAP4(m2, m3); CSWAP4(m0, m2); CSWAP4(m1, m3); CSWAP4(m1, m2);
        float4 hv = make_float4(cbv, cbv, cbv, cbv);
        hv = f4fma(c0, m0, hv);
        hv = f4fma(c1, m1, hv);
        hv = f4fma(c2, m2, hv);
        hv = f4fma(c3, m3, hv);
        hv = f4fma(aa, xv0, hv);
        h4[(size_t)v0 * DIM4 + d4] = hv;
        s  = f4add(s, hv);
        s2 = f4add(s2, make_float4(hv.x*hv.x, hv.y*hv.y, hv.z*hv.z, hv.w*hv.w));
    }
    {
        float4 m0 = (s1.x >= 0) ? g10 : bpv;
        float4 m1 = (s1.y >= 0) ? g11 : bpv;
        float4 m2 = (s1.z >= 0) ? g12 : bpv;
        float4 m3 = (s1.w >= 0) ? g13 : bpv;
        CSWAP4(m0, m1); CSWAP4(m2, m3); CSWAP4(m0, m2); CSWAP4(m1, m3); CSWAP4(m1, m2);
        float4 hv = make_float4(cbv, cbv, cbv, cbv);
        hv = f4fma(c0, m0, hv);
        hv = f4fma(c1, m1, hv);
        hv = f4fma(c2, m2, hv);
        hv = f4fma(c3, m3, hv);
        hv = f4fma(aa, xv1, hv);
        h4[(size_t)v1 * DIM4 + d4] = hv;
        s  = f4add(s, hv);
        s2 = f4add(s2, make_float4(hv.x*hv.x, hv.y*hv.y, hv.z*hv.z, hv.w*hv.w));
    }
    #undef CSWAP4

    // intra-wave: lane i += lane i+32 (same d4 column, different node)
    s.x  += __shfl_down(s.x, 32);  s.y  += __shfl_down(s.y, 32);
    s.z  += __shfl_down(s.z, 32);  s.w  += __shfl_down(s.w, 32);
    s2.x += __shfl_down(s2.x, 32); s2.y += __shfl_down(s2.y, 32);
    s2.z += __shfl_down(s2.z, 32); s2.w += __shfl_down(s2.w, 32);

    __shared__ float4 ls[4][32];
    __shared__ float4 ls2[4][32];
    const int wave = t >> 6;
    const int lane = t & 63;
    if (lane < 32) { ls[wave][lane] = s; ls2[wave][lane] = s2; }
    __syncthreads();
    if (t < 32) {
        float* bucket = stats_part + (size_t)(blockIdx.x & (NBUCKETS - 1)) * 256;
        float4 fs  = f4add(f4add(ls[0][t],  ls[1][t]),  f4add(ls[2][t],  ls[3][t]));
        float4 fs2 = f4add(f4add(ls2[0][t], ls2[1][t]), f4add(ls2[2][t], ls2[3][t]));
        atomicAdd(&bucket[4*t + 0], fs.x);
        atomicAdd(&bucket[4*t + 1], fs.y);
        atomicAdd(&bucket[4*t + 2], fs.z);
        atomicAdd(&bucket[4*t + 3], fs.w);
        atomicAdd(&bucket[DIM + 4*t + 0], fs2.x);
        atomicAdd(&bucket[DIM + 4*t + 1], fs2.y);
        atomicAdd(&bucket[DIM + 4*t + 2], fs2.z);
        atomicAdd(&bucket[DIM + 4*t + 3], fs2.w);
    }
}

// Sum the 64 bucket partials, finalize to mu (final[0:128]) and invstd (final[128:256]).
__global__ void reduce_finalize_kernel(const float* __restrict__ stats_part,
                                       float* __restrict__ final) {
    __shared__ float acc[256];
    int t = threadIdx.x;                 // 256 threads: t<128 sums, t>=128 sq-sums
    float s = 0.f;
    #pragma unroll 8
    for (int k = 0; k < NBUCKETS; ++k) s += stats_part[k * 256 + t];
    acc[t] = s;
    __syncthreads();
    if (t < 128) {
        constexpr float invN = 1.0f / (float)N_NODES;
        float mu = acc[t] * invN;
        float iv = rsqrtf(acc[128 + t] * invN - mu * mu + BN_EPS);
        final[t]       = mu;
        final[128 + t] = iv;
    }
}

// xout = xin + (h - mu) * invstd * g + be
__global__ void bn_apply_kernel(const float* __restrict__ xin,
                                const float* __restrict__ h,
                                const float* __restrict__ final,
                                const float* __restrict__ g,
                                const float* __restrict__ be,
                                float* __restrict__ xout) {
    int idx = blockIdx.x * blockDim.x + threadIdx.x;   // float4 index
    constexpr int TOTAL4 = N_NODES * DIM4;
    if (idx >= TOTAL4) return;
    int d4 = idx & (DIM4 - 1);

    float4 mu = ((const float4*)final)[d4];
    float4 iv = ((const float4*)(final + DIM))[d4];
    float4 hv = ((const float4*)h)[idx];
    float4 xv = ((const float4*)xin)[idx];
    float4 gv = ((const float4*)g)[d4];
    float4 bv = ((const float4*)be)[d4];

    float4 o;
    o.x = xv.x + (hv.x - mu.x) * iv.x * gv.x + bv.x;
    o.y = xv.y + (hv.y - mu.y) * iv.y * gv.y + bv.y;
    o.z = xv.z + (hv.z - mu.z) * iv.z * gv.z + bv.z;
    o.w = xv.w + (hv.w - mu.w) * iv.w * gv.w + bv.w;
    ((float4*)xout)[idx] = o;
}

extern "C" void kernel_launch(void* const* d_in, const int* in_sizes, int n_in,
                              void* d_out, int out_size, void* d_ws, size_t ws_size,
                              hipStream_t stream) {
    const float* x0  = (const float*)d_in[0];
    const int*   ei  = (const int*)d_in[1];
    const int*   src = ei;               // edge_index[0]
    const int*   dst = ei + N_EDGES;     // edge_index[1]

    const float* W[2]; const float* b[2]; const float* cw[2]; const float* cb[2];
    const float* a[2]; const float* g[2]; const float* be[2]; const float* blank[2];
    for (int i = 0; i < 2; ++i) {
        int o = 2 + 8 * i;
        W[i]     = (const float*)d_in[o + 0];
        b[i]     = (const float*)d_in[o + 1];
        cw[i]    = (const float*)d_in[o + 2];
        cb[i]    = (const float*)d_in[o + 3];
        a[i]     = (const float*)d_in[o + 4];
        g[i]     = (const float*)d_in[o + 5];
        be[i]    = (const float*)d_in[o + 6];
        blank[i] = (const float*)d_in[o + 7];
    }

    // Workspace layout (re-poisoned 0xAA each call — init everything used).
    // tables (stage A output, 16*N int4s = 12.8 MB) aliases the h region:
    // tables is dead before conv_stats writes h.
    char* ws = (char*)d_ws;
    int*   srcs       = (int*)ws;                                 // 4N ints, int4/node
    float* h          = (float*)(srcs + 4 * N_NODES);             // N*DIM floats = 25.6 MB
    int*   tables     = (int*)h;                                  // alias: 16*4N ints = 12.8 MB
    float* stats_part = h + (size_t)N_NODES * DIM;                // 2 * 64 * 256 floats
    float* final_     = stats_part + 2 * NBUCKETS * 256;          // 2 * 256 floats
    float* bp         = final_ + 512;                             // 256 floats (2 layers)

    float* xout = (float*)d_out;

    // ---- two-stage selection (LDS atomics only; streaming merge) ----
    select_stageA_kernel<<<NC * EC, SEL_THREADS, 0, stream>>>(dst, tables);
    select_stageB_kernel<<<NB_MERGE + 2, 256, 0, stream>>>(
        tables, src, (int4*)srcs, stats_part,
        W[0], b[0], blank[0], W[1], b[1], blank[1], bp);

    // ---- two layers ----
    for (int l = 0; l < 2; ++l) {
        const float* xin = (l == 0) ? x0 : xout;
        float* sp = stats_part + (size_t)l * NBUCKETS * 256;
        conv_stats_kernel<<<CONV_GRID, 256, 0, stream>>>(
            xin, (const int4*)srcs, bp + l * DIM, cw[l], cb[l], a[l], h, sp);
        reduce_finalize_kernel<<<1, 256, 0, stream>>>(sp, final_ + l * 256);
        bn_apply_kernel<<<(N_NODES * DIM4 + 255) / 256, 256, 0, stream>>>(
            xin, h, final_ + l * 256, g[l], be[l], xout);
    }
}